// Round 2
// baseline (4491.642 us; speedup 1.0000x reference)
//
#include <hip/hip_runtime.h>
#include <cmath>

// Problem constants (match reference setup_inputs exactly)
#define NCELL 50000
#define NGENE 2000
#define H1D   512
#define DD    128
#define CD    128
#define BN_EPS 1e-5f

// ---------------------------------------------------------------------------
// Library-size normalization: inv[n] = 10000 / sum_g x[n,g].  One wave/row.
// ---------------------------------------------------------------------------
__global__ void rowsum_kernel(const float* __restrict__ x, float* __restrict__ inv) {
    int wave = threadIdx.x >> 6;
    int lane = threadIdx.x & 63;
    int row = blockIdx.x * 4 + wave;
    if (row >= NCELL) return;
    const float* xr = x + (size_t)row * NGENE;
    float s = 0.f;
    for (int g = lane; g < NGENE; g += 64) s += xr[g];
    #pragma unroll
    for (int off = 32; off > 0; off >>= 1) s += __shfl_down(s, off, 64);
    if (lane == 0) inv[row] = 10000.0f / s;
}

// ---------------------------------------------------------------------------
// GEMM1: pre1[n,h] = (sum_g x[n,g] * W1[h,g]) * inv[n] + b1[h]
// M=50000, K=2000, P=512.  BM=BP=128, BK=16, 8x8 micro-tile, 256 threads.
// LDS k-major, stride 132 (2-way store aliasing only -> free).
// ---------------------------------------------------------------------------
__launch_bounds__(256, 2)
__global__ void gemm1_kernel(const float* __restrict__ X, const float* __restrict__ W,
                             const float* __restrict__ inv, const float* __restrict__ bias,
                             float* __restrict__ out) {
    __shared__ float As[16][132];
    __shared__ float Bs[16][132];
    const int tid = threadIdx.x;
    const int ty = tid >> 4, tx = tid & 15;
    const int row0 = blockIdx.y * 128;
    const int col0 = blockIdx.x * 128;
    float acc[8][8];
    #pragma unroll
    for (int i = 0; i < 8; ++i)
        #pragma unroll
        for (int j = 0; j < 8; ++j) acc[i][j] = 0.f;

    for (int k0 = 0; k0 < NGENE; k0 += 16) {
        #pragma unroll
        for (int l = 0; l < 2; ++l) {
            int idx = l * 256 + tid;
            int ar = idx >> 2, aq = idx & 3;
            int kl = aq * 4;
            int grow = row0 + ar;
            float4 va = make_float4(0.f, 0.f, 0.f, 0.f);
            if (grow < NCELL)
                va = *(const float4*)(X + (size_t)grow * NGENE + k0 + kl);
            As[kl + 0][ar] = va.x; As[kl + 1][ar] = va.y;
            As[kl + 2][ar] = va.z; As[kl + 3][ar] = va.w;
            float4 vb = *(const float4*)(W + (size_t)(col0 + ar) * NGENE + k0 + kl);
            Bs[kl + 0][ar] = vb.x; Bs[kl + 1][ar] = vb.y;
            Bs[kl + 2][ar] = vb.z; Bs[kl + 3][ar] = vb.w;
        }
        __syncthreads();
        #pragma unroll
        for (int kk = 0; kk < 16; ++kk) {
            float4 a0 = *(const float4*)&As[kk][ty * 8];
            float4 a1 = *(const float4*)&As[kk][ty * 8 + 4];
            float4 b0 = *(const float4*)&Bs[kk][tx * 8];
            float4 b1 = *(const float4*)&Bs[kk][tx * 8 + 4];
            float a[8] = {a0.x, a0.y, a0.z, a0.w, a1.x, a1.y, a1.z, a1.w};
            float b[8] = {b0.x, b0.y, b0.z, b0.w, b1.x, b1.y, b1.z, b1.w};
            #pragma unroll
            for (int i = 0; i < 8; ++i)
                #pragma unroll
                for (int j = 0; j < 8; ++j)
                    acc[i][j] = fmaf(a[i], b[j], acc[i][j]);
        }
        __syncthreads();
    }
    #pragma unroll
    for (int i = 0; i < 8; ++i) {
        int r = row0 + ty * 8 + i;
        if (r >= NCELL) break;
        float iv = inv[r];
        #pragma unroll
        for (int j = 0; j < 8; ++j) {
            int c = col0 + tx * 8 + j;
            out[(size_t)r * H1D + c] = fmaf(acc[i][j], iv, bias[c]);
        }
    }
}

// ---------------------------------------------------------------------------
// Column mean / mean-of-squares accumulation (for BatchNorm batch stats).
// stat[0..P) += sum, stat[P..2P) += sumsq.  blockDim must be 512, P | 512.
// ---------------------------------------------------------------------------
__global__ void colstats_kernel(const float* __restrict__ X, float* __restrict__ stat,
                                int P, int rows_per_block) {
    int tid = threadIdx.x;
    int step = 512 / P;
    int sub = tid / P;
    int c = tid - sub * P;
    int r0 = blockIdx.x * rows_per_block;
    int r1 = r0 + rows_per_block;
    if (r1 > NCELL) r1 = NCELL;
    float s1 = 0.f, s2 = 0.f;
    for (int r = r0 + sub; r < r1; r += step) {
        float v = X[(size_t)r * P + c];
        s1 += v;
        s2 += v * v;
    }
    atomicAdd(&stat[c], s1);
    atomicAdd(&stat[P + c], s2);
}

// bn[c] = g/sqrt(var+eps) ; bn[P+c] = be - mu*scale
__global__ void bnfinal_kernel(const float* __restrict__ stat, const float* __restrict__ g,
                               const float* __restrict__ be, float* __restrict__ bn, int P) {
    int c = blockIdx.x * blockDim.x + threadIdx.x;
    if (c >= P) return;
    float mu = stat[c] * (1.0f / NCELL);
    float var = stat[P + c] * (1.0f / NCELL) - mu * mu;
    float sc = g[c] * rsqrtf(var + BN_EPS);
    bn[c] = sc;
    bn[P + c] = be[c] - mu * sc;
}

// ---------------------------------------------------------------------------
// GEMM2: zpre[n,d] = sum_k relu(pre1[n,k]*sc1[k]+sh1[k]) * W2[d,k] + b2[d]
// M=50000, K=512, P=128.  BN+ReLU fused into A-tile staging.
// ---------------------------------------------------------------------------
__launch_bounds__(256, 2)
__global__ void gemm2_kernel(const float* __restrict__ X, const float* __restrict__ W,
                             const float* __restrict__ bn, const float* __restrict__ bias,
                             float* __restrict__ out) {
    __shared__ float As[16][132];
    __shared__ float Bs[16][132];
    const int tid = threadIdx.x;
    const int ty = tid >> 4, tx = tid & 15;
    const int row0 = blockIdx.y * 128;
    float acc[8][8];
    #pragma unroll
    for (int i = 0; i < 8; ++i)
        #pragma unroll
        for (int j = 0; j < 8; ++j) acc[i][j] = 0.f;

    for (int k0 = 0; k0 < H1D; k0 += 16) {
        #pragma unroll
        for (int l = 0; l < 2; ++l) {
            int idx = l * 256 + tid;
            int ar = idx >> 2, aq = idx & 3;
            int kl = aq * 4;
            int grow = row0 + ar;
            float4 va = make_float4(0.f, 0.f, 0.f, 0.f);
            if (grow < NCELL)
                va = *(const float4*)(X + (size_t)grow * H1D + k0 + kl);
            float4 sc = *(const float4*)(bn + k0 + kl);
            float4 sh = *(const float4*)(bn + H1D + k0 + kl);
            va.x = fmaxf(fmaf(va.x, sc.x, sh.x), 0.f);
            va.y = fmaxf(fmaf(va.y, sc.y, sh.y), 0.f);
            va.z = fmaxf(fmaf(va.z, sc.z, sh.z), 0.f);
            va.w = fmaxf(fmaf(va.w, sc.w, sh.w), 0.f);
            As[kl + 0][ar] = va.x; As[kl + 1][ar] = va.y;
            As[kl + 2][ar] = va.z; As[kl + 3][ar] = va.w;
            float4 vb = *(const float4*)(W + (size_t)ar * H1D + k0 + kl);
            Bs[kl + 0][ar] = vb.x; Bs[kl + 1][ar] = vb.y;
            Bs[kl + 2][ar] = vb.z; Bs[kl + 3][ar] = vb.w;
        }
        __syncthreads();
        #pragma unroll
        for (int kk = 0; kk < 16; ++kk) {
            float4 a0 = *(const float4*)&As[kk][ty * 8];
            float4 a1 = *(const float4*)&As[kk][ty * 8 + 4];
            float4 b0 = *(const float4*)&Bs[kk][tx * 8];
            float4 b1 = *(const float4*)&Bs[kk][tx * 8 + 4];
            float a[8] = {a0.x, a0.y, a0.z, a0.w, a1.x, a1.y, a1.z, a1.w};
            float b[8] = {b0.x, b0.y, b0.z, b0.w, b1.x, b1.y, b1.z, b1.w};
            #pragma unroll
            for (int i = 0; i < 8; ++i)
                #pragma unroll
                for (int j = 0; j < 8; ++j)
                    acc[i][j] = fmaf(a[i], b[j], acc[i][j]);
        }
        __syncthreads();
    }
    #pragma unroll
    for (int i = 0; i < 8; ++i) {
        int r = row0 + ty * 8 + i;
        if (r >= NCELL) break;
        #pragma unroll
        for (int j = 0; j < 8; ++j) {
            int c = tx * 8 + j;
            out[(size_t)r * DD + c] = acc[i][j] + bias[c];
        }
    }
}

// z = relu(zpre*sc2 + sh2), elementwise, float4.
__global__ void zrelu_kernel(const float* __restrict__ zpre, const float* __restrict__ bn,
                             float* __restrict__ z) {
    size_t idx = (size_t)blockIdx.x * 256 + threadIdx.x;   // over N*128/4
    float4 v = ((const float4*)zpre)[idx];
    int cb = ((int)idx & 31) * 4;
    v.x = fmaxf(fmaf(v.x, bn[cb + 0], bn[DD + cb + 0]), 0.f);
    v.y = fmaxf(fmaf(v.y, bn[cb + 1], bn[DD + cb + 1]), 0.f);
    v.z = fmaxf(fmaf(v.z, bn[cb + 2], bn[DD + cb + 2]), 0.f);
    v.w = fmaxf(fmaf(v.w, bn[cb + 3], bn[DD + cb + 3]), 0.f);
    ((float4*)z)[idx] = v;
}

// ---------------------------------------------------------------------------
// edge_index dtype detector: JAX may hand us int32 (x64 off) or int64.
// If int64 (LE), every odd int32 word of the first E values is a zero high
// word.  Over 800K samples P(false positive | int32) ~ e^-16.
// flag stays 0 -> int64; flag=1 -> int32.
// ---------------------------------------------------------------------------
__global__ void detect64_kernel(const int* __restrict__ ei32, int nPairs,
                                int* __restrict__ flag) {
    int i = blockIdx.x * 256 + threadIdx.x;
    int v = 0;
    if (i < nPairs) v = ei32[2 * i + 1];
    if (__any(v != 0)) {
        if ((threadIdx.x & 63) == 0) atomicOr(flag, 1);
    }
}

// Mean-aggregation scatter: agg[dst,:] += z[src,:], cnt[dst] += 1.
// One thread per (edge, dim).  fp32 atomics (device scope, XCD-safe).
__global__ void edge_kernel(const int* __restrict__ ei32, const float* __restrict__ z,
                            const int* __restrict__ flag, float* __restrict__ agg,
                            float* __restrict__ cnt, int E) {
    long long gid = (long long)blockIdx.x * 256 + threadIdx.x;
    long long e = gid >> 7;
    int d = (int)(gid & 127);
    if (e >= E) return;
    int src, dst;
    if (*flag) {                       // int32 layout [2][E]
        src = ei32[e];
        dst = ei32[E + e];
    } else {                           // int64 layout: take low words
        src = ei32[2 * e];
        dst = ei32[2 * (E + e)];
    }
    atomicAdd(&agg[(size_t)dst * DD + d], z[(size_t)src * DD + d]);
    if (d == 0) atomicAdd(&cnt[dst], 1.0f);
}

// ---------------------------------------------------------------------------
// SAGE + common-subtract fused GEMM:
// zu[n,c] = relu( (agg[n,:]/max(cnt,1))@Wl.T + z@Wr.T - xz@Wc.T + bl )[c]
// 3-phase K=384 loop.  Output straight to d_out.
// ---------------------------------------------------------------------------
__launch_bounds__(256, 2)
__global__ void sage_kernel(const float* __restrict__ agg, const float* __restrict__ cnt,
                            const float* __restrict__ z, const float* __restrict__ xz,
                            const float* __restrict__ Wl, const float* __restrict__ Wr,
                            const float* __restrict__ Wc, const float* __restrict__ bl,
                            float* __restrict__ out) {
    __shared__ float As[16][132];
    __shared__ float Bs[16][132];
    const int tid = threadIdx.x;
    const int ty = tid >> 4, tx = tid & 15;
    const int row0 = blockIdx.y * 128;
    float acc[8][8];
    #pragma unroll
    for (int i = 0; i < 8; ++i)
        #pragma unroll
        for (int j = 0; j < 8; ++j) acc[i][j] = 0.f;

    for (int k0 = 0; k0 < 384; k0 += 16) {
        int ph = k0 >> 7;
        int kbase = k0 & 127;
        const float* Aptr = ph == 0 ? agg : (ph == 1 ? z : xz);
        const float* Bptr = ph == 0 ? Wl : (ph == 1 ? Wr : Wc);
        #pragma unroll
        for (int l = 0; l < 2; ++l) {
            int idx = l * 256 + tid;
            int ar = idx >> 2, aq = idx & 3;
            int kl = aq * 4;
            int grow = row0 + ar;
            float4 va = make_float4(0.f, 0.f, 0.f, 0.f);
            if (grow < NCELL) {
                va = *(const float4*)(Aptr + (size_t)grow * DD + kbase + kl);
                if (ph == 0) {
                    float rc = 1.0f / fmaxf(cnt[grow], 1.0f);
                    va.x *= rc; va.y *= rc; va.z *= rc; va.w *= rc;
                } else if (ph == 2) {
                    va.x = -va.x; va.y = -va.y; va.z = -va.z; va.w = -va.w;
                }
            }
            As[kl + 0][ar] = va.x; As[kl + 1][ar] = va.y;
            As[kl + 2][ar] = va.z; As[kl + 3][ar] = va.w;
            float4 vb = *(const float4*)(Bptr + (size_t)ar * DD + kbase + kl);
            Bs[kl + 0][ar] = vb.x; Bs[kl + 1][ar] = vb.y;
            Bs[kl + 2][ar] = vb.z; Bs[kl + 3][ar] = vb.w;
        }
        __syncthreads();
        #pragma unroll
        for (int kk = 0; kk < 16; ++kk) {
            float4 a0 = *(const float4*)&As[kk][ty * 8];
            float4 a1 = *(const float4*)&As[kk][ty * 8 + 4];
            float4 b0 = *(const float4*)&Bs[kk][tx * 8];
            float4 b1 = *(const float4*)&Bs[kk][tx * 8 + 4];
            float a[8] = {a0.x, a0.y, a0.z, a0.w, a1.x, a1.y, a1.z, a1.w};
            float b[8] = {b0.x, b0.y, b0.z, b0.w, b1.x, b1.y, b1.z, b1.w};
            #pragma unroll
            for (int i = 0; i < 8; ++i)
                #pragma unroll
                for (int j = 0; j < 8; ++j)
                    acc[i][j] = fmaf(a[i], b[j], acc[i][j]);
        }
        __syncthreads();
    }
    #pragma unroll
    for (int i = 0; i < 8; ++i) {
        int r = row0 + ty * 8 + i;
        if (r >= NCELL) break;
        #pragma unroll
        for (int j = 0; j < 8; ++j) {
            int c = tx * 8 + j;
            out[(size_t)r * DD + c] = fmaxf(acc[i][j] + bl[c], 0.f);
        }
    }
}

// batch_pred[n,j] = zu[n,:]@Wb[j,:] + bb[j].  One wave per row, 4 dots.
__global__ void batchpred_kernel(const float* __restrict__ zu, const float* __restrict__ Wb,
                                 const float* __restrict__ bb, float* __restrict__ out) {
    int wave = threadIdx.x >> 6;
    int lane = threadIdx.x & 63;
    int row = blockIdx.x * 4 + wave;
    if (row >= NCELL) return;
    float z0 = zu[(size_t)row * DD + lane];
    float z1 = zu[(size_t)row * DD + 64 + lane];
    #pragma unroll
    for (int j = 0; j < 4; ++j) {
        float p = z0 * Wb[j * DD + lane] + z1 * Wb[j * DD + 64 + lane];
        #pragma unroll
        for (int off = 32; off > 0; off >>= 1) p += __shfl_down(p, off, 64);
        if (lane == 0) out[(size_t)row * 4 + j] = p + bb[j];
    }
}

// ---------------------------------------------------------------------------
// Final dual GEMM: h2 = [xz | zu] (K=256), against Ws AND Wd per A-tile.
// px_scale = exp(h2@Ws.T+bs), px_dropout = h2@Wd.T+bd.
// M=50000, K=256, P=2000.  BM=128, BP=64, 8x4 micro-tile x2 outputs.
// ---------------------------------------------------------------------------
__launch_bounds__(256, 2)
__global__ void final_kernel(const float* __restrict__ xz, const float* __restrict__ zu,
                             const float* __restrict__ Ws, const float* __restrict__ Wd,
                             const float* __restrict__ bs, const float* __restrict__ bd,
                             float* __restrict__ o_ps, float* __restrict__ o_pd) {
    __shared__ float As[16][132];
    __shared__ float B1s[16][68];
    __shared__ float B2s[16][68];
    const int tid = threadIdx.x;
    const int ty = tid >> 4, tx = tid & 15;
    const int row0 = blockIdx.y * 128;
    const int col0 = blockIdx.x * 64;
    float acc1[8][4], acc2[8][4];
    #pragma unroll
    for (int i = 0; i < 8; ++i)
        #pragma unroll
        for (int j = 0; j < 4; ++j) { acc1[i][j] = 0.f; acc2[i][j] = 0.f; }

    for (int k0 = 0; k0 < 256; k0 += 16) {
        int ph = k0 >> 7;
        int kbase = k0 & 127;
        const float* Aptr = ph == 0 ? xz : zu;
        #pragma unroll
        for (int l = 0; l < 2; ++l) {
            int idx = l * 256 + tid;
            int ar = idx >> 2, aq = idx & 3;
            int kl = aq * 4;
            int grow = row0 + ar;
            float4 va = make_float4(0.f, 0.f, 0.f, 0.f);
            if (grow < NCELL)
                va = *(const float4*)(Aptr + (size_t)grow * DD + kbase + kl);
            As[kl + 0][ar] = va.x; As[kl + 1][ar] = va.y;
            As[kl + 2][ar] = va.z; As[kl + 3][ar] = va.w;
        }
        {
            int br = tid >> 2, bq = tid & 3;
            int kl = bq * 4;
            int gcol = col0 + br;
            float4 v1 = make_float4(0.f, 0.f, 0.f, 0.f);
            float4 v2 = v1;
            if (gcol < NGENE) {
                v1 = *(const float4*)(Ws + (size_t)gcol * 256 + k0 + kl);
                v2 = *(const float4*)(Wd + (size_t)gcol * 256 + k0 + kl);
            }
            B1s[kl + 0][br] = v1.x; B1s[kl + 1][br] = v1.y;
            B1s[kl + 2][br] = v1.z; B1s[kl + 3][br] = v1.w;
            B2s[kl + 0][br] = v2.x; B2s[kl + 1][br] = v2.y;
            B2s[kl + 2][br] = v2.z; B2s[kl + 3][br] = v2.w;
        }
        __syncthreads();
        #pragma unroll
        for (int kk = 0; kk < 16; ++kk) {
            float4 a0 = *(const float4*)&As[kk][ty * 8];
            float4 a1 = *(const float4*)&As[kk][ty * 8 + 4];
            float4 b1 = *(const float4*)&B1s[kk][tx * 4];
            float4 b2 = *(const float4*)&B2s[kk][tx * 4];
            float a[8] = {a0.x, a0.y, a0.z, a0.w, a1.x, a1.y, a1.z, a1.w};
            float p[4] = {b1.x, b1.y, b1.z, b1.w};
            float q[4] = {b2.x, b2.y, b2.z, b2.w};
            #pragma unroll
            for (int i = 0; i < 8; ++i)
                #pragma unroll
                for (int j = 0; j < 4; ++j) {
                    acc1[i][j] = fmaf(a[i], p[j], acc1[i][j]);
                    acc2[i][j] = fmaf(a[i], q[j], acc2[i][j]);
                }
        }
        __syncthreads();
    }
    #pragma unroll
    for (int i = 0; i < 8; ++i) {
        int r = row0 + ty * 8 + i;
        if (r >= NCELL) break;
        #pragma unroll
        for (int j = 0; j < 4; ++j) {
            int c = col0 + tx * 4 + j;
            if (c < NGENE) {
                o_ps[(size_t)r * NGENE + c] = expf(acc1[i][j] + bs[c]);
                o_pd[(size_t)r * NGENE + c] = acc2[i][j] + bd[c];
            }
        }
    }
}

__global__ void exprate_kernel(const float* __restrict__ disp, float* __restrict__ out) {
    int i = blockIdx.x * 256 + threadIdx.x;
    if (i < NGENE) out[i] = expf(disp[i]);
}

// ---------------------------------------------------------------------------
extern "C" void kernel_launch(void* const* d_in, const int* in_sizes, int n_in,
                              void* d_out, int out_size, void* d_ws, size_t ws_size,
                              hipStream_t stream) {
    const float* x_c1 = (const float*)d_in[0];
    const float* xz   = (const float*)d_in[1];
    const int*   ei32 = (const int*)d_in[2];
    const float* W1 = (const float*)d_in[3];
    const float* b1 = (const float*)d_in[4];
    const float* g1 = (const float*)d_in[5];
    const float* be1 = (const float*)d_in[6];
    const float* W2 = (const float*)d_in[7];
    const float* b2 = (const float*)d_in[8];
    const float* g2 = (const float*)d_in[9];
    const float* be2 = (const float*)d_in[10];
    const float* Wl = (const float*)d_in[11];
    const float* bl = (const float*)d_in[12];
    const float* Wr = (const float*)d_in[13];
    const float* Wc = (const float*)d_in[14];
    const float* Wsm = (const float*)d_in[15];
    const float* bs = (const float*)d_in[16];
    const float* Wdm = (const float*)d_in[17];
    const float* bd = (const float*)d_in[18];
    const float* disp = (const float*)d_in[19];
    const float* Wb = (const float*)d_in[20];
    const float* bb = (const float*)d_in[21];
    const int E = in_sizes[2] / 2;                 // 800000

    // d_out layout: (z_unique, px_scale, px_rate, px_dropout, batch_pred)
    float* out = (float*)d_out;
    float* o_zu = out;                             // 6,400,000
    float* o_ps = out + 6400000;                   // 100,000,000
    float* o_pr = o_ps + 100000000;                // 2,000
    float* o_pd = o_pr + 2000;                     // 100,000,000
    float* o_bp = o_pd + 100000000;                // 200,000

    // ALL scratch lives inside o_ps / o_pd (each 100M floats) — both regions
    // are written only by final_kernel, the last kernel; every intermediate is
    // dead by then.  d_ws is untouched (no dependence on ws_size).
    float* pre1  = o_ps;                           // 25,600,000
    float* zpre  = o_ps + 25600000;                // 6,400,000
    float* z     = o_ps + 32000000;                // 6,400,000
    float* inv   = o_ps + 38400000;                // 50,048
    float* stat1 = o_ps + 38450048;                // 1,024
    float* bn1   = stat1 + 1024;                   // 1,024
    float* stat2 = bn1 + 1024;                     // 256
    float* bn2   = stat2 + 256;                    // 256
    int*   flag  = (int*)(bn2 + 256);              // 1
    float* agg   = o_pd;                           // 6,400,000
    float* cnt   = o_pd + 6400000;                 // 50,000

    hipMemsetAsync(flag, 0, sizeof(int), stream);
    hipMemsetAsync(stat1, 0, 1024 * sizeof(float), stream);
    hipMemsetAsync(stat2, 0, 256 * sizeof(float), stream);

    detect64_kernel<<<(E + 255) / 256, 256, 0, stream>>>(ei32, E, flag);
    rowsum_kernel<<<(NCELL + 3) / 4, 256, 0, stream>>>(x_c1, inv);
    gemm1_kernel<<<dim3(4, 391), 256, 0, stream>>>(x_c1, W1, inv, b1, pre1);
    colstats_kernel<<<500, 512, 0, stream>>>(pre1, stat1, 512, 100);
    bnfinal_kernel<<<1, 512, 0, stream>>>(stat1, g1, be1, bn1, 512);
    gemm2_kernel<<<dim3(1, 391), 256, 0, stream>>>(pre1, W2, bn1, b2, zpre);
    colstats_kernel<<<500, 512, 0, stream>>>(zpre, stat2, 128, 100);
    bnfinal_kernel<<<1, 128, 0, stream>>>(stat2, g2, be2, bn2, 128);
    zrelu_kernel<<<6250, 256, 0, stream>>>(zpre, bn2, z);

    hipMemsetAsync(agg, 0, (size_t)6400000 * sizeof(float), stream);
    hipMemsetAsync(cnt, 0, (size_t)50000 * sizeof(float), stream);
    edge_kernel<<<(int)(((long long)E * 128 + 255) / 256), 256, 0, stream>>>(
        ei32, z, flag, agg, cnt, E);

    sage_kernel<<<dim3(1, 391), 256, 0, stream>>>(agg, cnt, z, xz, Wl, Wr, Wc, bl, o_zu);
    batchpred_kernel<<<(NCELL + 3) / 4, 256, 0, stream>>>(o_zu, Wb, bb, o_bp);
    final_kernel<<<dim3(32, 391), 256, 0, stream>>>(xz, o_zu, Wsm, Wdm, bs, bd, o_ps, o_pd);
    exprate_kernel<<<8, 256, 0, stream>>>(disp, o_pr);
}